// Round 20
// baseline (697.719 us; speedup 1.0000x reference)
//
#include <hip/hip_runtime.h>

#define HH 128
#define WW 128

typedef __bf16 bf16;
typedef bf16 bf16x8 __attribute__((ext_vector_type(8)));
typedef float f32x4 __attribute__((ext_vector_type(4)));

__device__ __forceinline__ float hsig(float x) {
    return fminf(fmaxf(fmaf(0.2f, x, 0.5f), 0.f), 1.f);
}
__device__ __forceinline__ float ftanh(float x) {
    const float u = __expf(2.f * fminf(x, 40.f));
    return (u - 1.f) * __builtin_amdgcn_rcpf(u + 1.f);
}
__device__ __forceinline__ bf16x8 zero8() {
    bf16x8 z;
    #pragma unroll
    for (int j = 0; j < 8; ++j) z[j] = (bf16)0.f;
    return z;
}

// ---- one-time weight prep: fp32 [tap][ci][cout] -> bf16 Wt[l][tap][cout][ci64]
// Unified ci64 layout: input cins [0,CX) (CX=16 for l0, else 32), zeros [CX,32),
// own-h cins [32,64).
__global__ void prep_weights(const float* __restrict__ Wx0, const float* __restrict__ Wh0,
                             const float* __restrict__ Wx1, const float* __restrict__ Wh1,
                             const float* __restrict__ Wx2, const float* __restrict__ Wh2,
                             const float* __restrict__ Wx3, const float* __restrict__ Wh3,
                             bf16* __restrict__ Wt)
{
    int idx = blockIdx.x * 256 + threadIdx.x;      // 4*9*128*64 = 294912
    if (idx >= 4 * 9 * 128 * 64) return;
    const int l = idx / 73728;
    int r = idx - l * 73728;
    const int tap = r / (128 * 64);
    r -= tap * 128 * 64;
    const int co = r >> 6;
    const int ci = r & 63;
    const int CX = (l == 0) ? 16 : 32;
    const float* Wx = (l == 0) ? Wx0 : (l == 1) ? Wx1 : (l == 2) ? Wx2 : Wx3;
    const float* Wh = (l == 0) ? Wh0 : (l == 1) ? Wh1 : (l == 2) ? Wh2 : Wh3;
    float v = 0.f;
    if (ci < 32) { if (ci < CX) v = Wx[((size_t)tap * CX + ci) * 128 + co]; }
    else          v = Wh[((size_t)tap * 32 + (ci - 32)) * 128 + co];
    Wt[(size_t)l * 73728 + ((size_t)tap * 128 + co) * 64 + ci] = (bf16)v;
}

constexpr int ST = 72;   // ci stride (elems) in LDS halo

// Diagonal-wavefront ConvLSTM stage kernel, 3-waves/SIMD variant:
// tile 16x4, 2 waves, M=64/wave, N=64 parity split -> acc[4][4] = 64 AGPR.
// VGPR trimmed <=106: staging 4+3 (32V), SINGLE B buffer (32V),
// c prefetch moved to epilogue via contiguous per-thread blob (16V late).
// launch_bounds(128,3): 12 waves/CU, 6 blocks/CU (LDS 15.5KB).
__global__ __launch_bounds__(128, 3)
void lstm_stage(const float* __restrict__ x,
                const bf16* __restrict__ Wt,
                const float* __restrict__ b0, const float* __restrict__ b1,
                const float* __restrict__ b2, const float* __restrict__ b3,
                bf16* __restrict__ h0, bf16* __restrict__ h1,
                bf16* __restrict__ h2, bf16* __restrict__ h3,
                float* __restrict__ cbase,
                float* __restrict__ outf,
                const int d, const int lmin)
{
    __shared__ bf16 sact[108 * ST];        // halo 6y x 18x pixels, 64 ci each

    const int tid = threadIdx.x;
    const int bx = blockIdx.x, by = blockIdx.y;
    const int s  = blockIdx.z >> 2, bb = blockIdx.z & 3;
    const int l  = lmin + s;
    const int t  = d - l;

    const size_t S = (size_t)4 * HH * WW * 32;
    bf16* hlbase = (l == 0) ? h0 : (l == 1) ? h1 : (l == 2) ? h2 : h3;
    bf16*       hcur = hlbase + (size_t)((l == 0) ? (t & 3) : (t & 1)) * S;
    const bf16* hprv = hlbase + (size_t)((l == 0) ? ((t + 3) & 3) : ((t + 1) & 1)) * S;
    const bf16* hin  = (l == 1) ? h0 + (size_t)(t & 3) * S
                     : (l == 2) ? h1 + (size_t)(t & 1) * S
                     : (l == 3) ? h2 + (size_t)(t & 1) * S : nullptr;
    const bf16* resp = h0 + (size_t)(t & 3) * S;           // layer0 h at t (l==3)
    const float* bias = (l == 0) ? b0 : (l == 1) ? b1 : (l == 2) ? b2 : b3;

    const int lane = tid & 63;
    const int p    = tid >> 6;        // wave parity: nb = p + 2q
    const int col  = lane & 15;       // A row (x) / C col / B col
    const int krow = lane >> 4;       // k-slice / C row block
    const int abase = col * ST + krow * 8;
    const int x0 = bx * 16 + krow * 4;
    const int f  = p * 16 + col;

    const size_t pb0 = (((size_t)bb * HH + by * 4) * WW + x0) * 32 + f;
    const bf16* __restrict__ wb0 = Wt + (size_t)l * 73728 + (size_t)(p * 16 + col) * 64 + krow * 8;

    // per-thread private c blob: [l][bb][by][bx][tid][16]
    float* cblob = cbase
        + (((((size_t)l * 4 + bb) * 32 + by) * 8 + bx) * 128 + tid) * 16;

    bf16x8 B0[2][4];   // SINGLE B buffer (register budget for 3 waves/SIMD)

#define LOAD_B(tap) do {                                                     \
        const bf16* wt_ = wb0 + (size_t)(tap) * 8192;                        \
        _Pragma("unroll")                                                    \
        for (int q_ = 0; q_ < 4; ++q_) {                                     \
            B0[0][q_] = *(const bf16x8*)(wt_ + q_ * 2048);                   \
            B0[1][q_] = *(const bf16x8*)(wt_ + q_ * 2048 + 32);              \
        }                                                                    \
    } while (0)

    // ---- EARLY: tap-0 weights in flight before staging ----
    LOAD_B(0);

    // ---- staging: 864 items / 128 thr = 6.75 -> 7; split 4 + 3 ----
    auto load_item = [&](int k, bf16x8& RH, bf16x8& RR) {
        RH = zero8(); RR = zero8();
        const int i = tid + k * 128;
        if (i < 108 * 8) {
            const int pix = i >> 3, g = i & 7;
            const int hy = pix / 18, hx = pix - hy * 18;
            const int sy = by * 4 - 1 + hy, sx = bx * 16 - 1 + hx;
            if (((unsigned)sy < HH) && ((unsigned)sx < WW)) {
                const size_t poff = (size_t)sy * WW + sx;
                if (g < 4) {
                    if (l == 0) {
                        if (g < 2) {               // raw-bit load of 8 fp32
                            const float* xp = x + ((size_t)(bb * 8 + t) * HH * WW + poff) * 16 + g * 8;
                            RH = *(const bf16x8*)xp;        // x[0..3] bits
                            RR = *(const bf16x8*)(xp + 4);  // x[4..7] bits
                        }
                    } else {
                        RH = *(const bf16x8*)(hin + ((size_t)bb * HH * WW + poff) * 32 + g * 8);
                        if (l == 3)
                            RR = *(const bf16x8*)(resp + ((size_t)bb * HH * WW + poff) * 32 + g * 8);
                    }
                } else if (t > 0) {
                    RH = *(const bf16x8*)(hprv + ((size_t)bb * HH * WW + poff) * 32 + (g - 4) * 8);
                }
            }
        }
    };
    auto store_item = [&](int k, const bf16x8& RH, const bf16x8& RR) {
        const int i = tid + k * 128;
        if (i < 108 * 8) {
            const int pix = i >> 3, g = i & 7;
            bf16x8 w;
            if (g < 4 && l == 0) {
                if (g < 2) {                      // bit-cast back, convert to bf16
                    const f32x4 a = __builtin_bit_cast(f32x4, RH);
                    const f32x4 b = __builtin_bit_cast(f32x4, RR);
                    w[0] = (bf16)a.x; w[1] = (bf16)a.y; w[2] = (bf16)a.z; w[3] = (bf16)a.w;
                    w[4] = (bf16)b.x; w[5] = (bf16)b.y; w[6] = (bf16)b.z; w[7] = (bf16)b.w;
                } else {
                    w = RH;                       // zero pad
                }
            } else if (g < 4 && l == 3) {         // residual add + relu
                #pragma unroll
                for (int j = 0; j < 8; ++j)
                    w[j] = (bf16)fmaxf((float)RH[j] + (float)RR[j], 0.f);
            } else if (g < 4 && l == 2) {         // relu only
                #pragma unroll
                for (int j = 0; j < 8; ++j)
                    w[j] = (bf16)fmaxf((float)RH[j], 0.f);
            } else {
                w = RH;                           // pure copy
            }
            *(bf16x8*)(&sact[pix * ST + g * 8]) = w;
        }
    };

    {
        bf16x8 rh[4], rr[4];
        #pragma unroll
        for (int k = 0; k < 4; ++k) load_item(k, rh[k], rr[k]);
        #pragma unroll
        for (int k = 0; k < 4; ++k) store_item(k, rh[k], rr[k]);
        #pragma unroll
        for (int k = 4; k < 7; ++k) load_item(k, rh[k - 4], rr[k - 4]);
        #pragma unroll
        for (int k = 4; k < 7; ++k) store_item(k, rh[k - 4], rr[k - 4]);
    }
    __syncthreads();

    f32x4 acc2[4][4];                 // [mt = row][q = gate]  (64 AGPR)
    #pragma unroll
    for (int q = 0; q < 4; ++q) {
        const float bv = bias[(p + 2 * q) * 16 + col];
        #pragma unroll
        for (int mt = 0; mt < 4; ++mt) acc2[mt][q] = (f32x4){bv, bv, bv, bv};
    }

    // per tap: load B (single buffer), stream A per-mt, 32 MFMA
#define MFMA_TAP(tap) do {                                                   \
        const int dy_ = (tap) / 3, dx_ = (tap) - dy_ * 3;                    \
        const int o_ = abase + (dy_ * 18 + dx_) * ST;                        \
        _Pragma("unroll")                                                    \
        for (int mt_ = 0; mt_ < 4; ++mt_) {                                  \
            const bf16x8 Aa = *(const bf16x8*)(&sact[o_ + mt_ * 18 * ST]);    \
            const bf16x8 Ab = *(const bf16x8*)(&sact[o_ + mt_ * 18 * ST + 32]);\
            __builtin_amdgcn_s_setprio(1);                                   \
            _Pragma("unroll")                                                \
            for (int q_ = 0; q_ < 4; ++q_)                                   \
                acc2[mt_][q_] = __builtin_amdgcn_mfma_f32_16x16x32_bf16(     \
                    Aa, B0[0][q_], acc2[mt_][q_], 0, 0, 0);                  \
            _Pragma("unroll")                                                \
            for (int q_ = 0; q_ < 4; ++q_)                                   \
                acc2[mt_][q_] = __builtin_amdgcn_mfma_f32_16x16x32_bf16(     \
                    Ab, B0[1][q_], acc2[mt_][q_], 0, 0, 0);                  \
            __builtin_amdgcn_s_setprio(0);                                   \
        }                                                                    \
    } while (0)

    MFMA_TAP(0);
    #pragma unroll 1
    for (int tap = 1; tap < 9; ++tap) {
        LOAD_B(tap);
        MFMA_TAP(tap);
    }

#undef LOAD_B
#undef MFMA_TAP

    // ---- epilogue: c loaded LATE (blob, 4 f32x4), lane-local LSTM math ----
    f32x4 cpre4[4];
    #pragma unroll
    for (int i = 0; i < 4; ++i) cpre4[i] = (f32x4){0.f, 0.f, 0.f, 0.f};
    if (t > 0) {
        #pragma unroll
        for (int i = 0; i < 4; ++i) cpre4[i] = ((const f32x4*)cblob)[i];
    }

    f32x4 cn4[4];
    #pragma unroll
    for (int mt = 0; mt < 4; ++mt) {
        #pragma unroll
        for (int j = 0; j < 4; ++j) {
            const size_t pb = pb0 + (size_t)(mt * WW + j) * 32;
            const float zi = acc2[mt][0][j];
            const float zf = acc2[mt][1][j];
            const float zg = acc2[mt][2][j];
            const float zo = acc2[mt][3][j];
            const float ig = hsig(zi), fg = hsig(zf);
            const float gg = ftanh(zg), og = hsig(zo);
            const float cn = fmaf(fg, cpre4[mt][j], ig * gg);
            cn4[mt][j] = cn;
            const float hn = og * ftanh(cn);
            if (l == 3 && t == 7) outf[pb] = hn;
            else                  hcur[pb] = (bf16)hn;
        }
    }
    if (t != 7) {                      // c(8) never read
        #pragma unroll
        for (int i = 0; i < 4; ++i) ((f32x4*)cblob)[i] = cn4[i];
    }
}

extern "C" void kernel_launch(void* const* d_in, const int* in_sizes, int n_in,
                              void* d_out, int out_size, void* d_ws, size_t ws_size,
                              hipStream_t stream) {
    const float* x = (const float*)d_in[0];
    const float* Wx[4] = {(const float*)d_in[1], (const float*)d_in[4],
                          (const float*)d_in[7], (const float*)d_in[10]};
    const float* Wh[4] = {(const float*)d_in[2], (const float*)d_in[5],
                          (const float*)d_in[8], (const float*)d_in[11]};
    const float* bs[4] = {(const float*)d_in[3], (const float*)d_in[6],
                          (const float*)d_in[9], (const float*)d_in[12]};
    float* out = (float*)d_out;

    const size_t S  = (size_t)4 * HH * WW * 32;   // one [B,H,W,32] buffer (elements)
    const size_t WT = (size_t)4 * 73728;          // transposed weights (bf16 elems)

    bf16* wt = (bf16*)d_ws;
    bf16* h0 = wt + WT;              // layer0: 4-deep ring (residual read at d+3)
    bf16* h1 = h0 + 4 * S;           // layers 1..3: 2-deep rings
    bf16* h2 = h1 + 2 * S;
    bf16* h3 = h2 + 2 * S;
    float* cb = (float*)(h3 + 2 * S);   // c blobs: 4l x 4bb x 256 tiles x 128 thr x 16 f32

    prep_weights<<<1152, 256, 0, stream>>>(Wx[0], Wh[0], Wx[1], Wh[1],
                                           Wx[2], Wh[2], Wx[3], Wh[3], wt);

    // Diagonal wavefront: d = t + l, stages (t, l) on one diagonal are independent.
    for (int d = 0; d <= 10; ++d) {
        const int lmin = (d > 7) ? (d - 7) : 0;
        const int lmax = (d < 3) ? d : 3;
        const int nst  = lmax - lmin + 1;
        dim3 grid(WW / 16, HH / 4, nst * 4);
        lstm_stage<<<grid, dim3(128), 0, stream>>>(
            x, wt, bs[0], bs[1], bs[2], bs[3],
            h0, h1, h2, h3, cb, out, d, lmin);
    }
}

// Round 21
// 586.019 us; speedup vs baseline: 1.1906x; 1.1906x over previous
//
#include <hip/hip_runtime.h>

#define HH 128
#define WW 128

typedef __bf16 bf16;
typedef bf16 bf16x4 __attribute__((ext_vector_type(4)));
typedef bf16 bf16x8 __attribute__((ext_vector_type(8)));
typedef float f32x4 __attribute__((ext_vector_type(4)));

__device__ __forceinline__ float hsig(float x) {
    return fminf(fmaxf(fmaf(0.2f, x, 0.5f), 0.f), 1.f);
}
__device__ __forceinline__ float ftanh(float x) {
    const float u = __expf(2.f * fminf(x, 40.f));
    return (u - 1.f) * __builtin_amdgcn_rcpf(u + 1.f);
}
__device__ __forceinline__ bf16x8 zero8() {
    bf16x8 z;
    #pragma unroll
    for (int j = 0; j < 8; ++j) z[j] = (bf16)0.f;
    return z;
}

// ---- one-time weight prep: fp32 [tap][ci][cout] -> bf16 Wt[l][tap][cout][ci64]
// Unified ci64 layout: input cins [0,CX) (CX=16 for l0, else 32), zeros [CX,32),
// own-h cins [32,64).
__global__ void prep_weights(const float* __restrict__ Wx0, const float* __restrict__ Wh0,
                             const float* __restrict__ Wx1, const float* __restrict__ Wh1,
                             const float* __restrict__ Wx2, const float* __restrict__ Wh2,
                             const float* __restrict__ Wx3, const float* __restrict__ Wh3,
                             bf16* __restrict__ Wt)
{
    int idx = blockIdx.x * 256 + threadIdx.x;      // 4*9*128*64 = 294912
    if (idx >= 4 * 9 * 128 * 64) return;
    const int l = idx / 73728;
    int r = idx - l * 73728;
    const int tap = r / (128 * 64);
    r -= tap * 128 * 64;
    const int co = r >> 6;
    const int ci = r & 63;
    const int CX = (l == 0) ? 16 : 32;
    const float* Wx = (l == 0) ? Wx0 : (l == 1) ? Wx1 : (l == 2) ? Wx2 : Wx3;
    const float* Wh = (l == 0) ? Wh0 : (l == 1) ? Wh1 : (l == 2) ? Wh2 : Wh3;
    float v = 0.f;
    if (ci < 32) { if (ci < CX) v = Wx[((size_t)tap * CX + ci) * 128 + co]; }
    else          v = Wh[((size_t)tap * 32 + (ci - 32)) * 128 + co];
    Wt[(size_t)l * 73728 + ((size_t)tap * 128 + co) * 64 + ci] = (bf16)v;
}

constexpr int ST = 74;   // ci stride (elems): 37 words = 5 mod 32 -> <=2-way banks

// Diagonal-wavefront ConvLSTM stage kernel, M=128/wave (R18 structure) with:
// (1) ST=74 (A-read bank conflicts 8-way -> <=2-way, free);
// (2) SWAPPED MFMA operands (C^T, same fragments): thread owns 4 consecutive
//     filters at one pixel -> f32x4 c load/store in canonical layout,
//     bf16x4 h stores, f32x4 bias seeds / outf stores.
__global__ __launch_bounds__(128, 2)
void lstm_stage(const float* __restrict__ x,
                const bf16* __restrict__ Wt,
                const float* __restrict__ b0, const float* __restrict__ b1,
                const float* __restrict__ b2, const float* __restrict__ b3,
                bf16* __restrict__ h0, bf16* __restrict__ h1,
                bf16* __restrict__ h2, bf16* __restrict__ h3,
                float* __restrict__ cbase,
                float* __restrict__ outf,
                const int d, const int lmin)
{
    __shared__ bf16 sact[180 * ST];        // halo 10y x 18x pixels, 64 ci each

    const int tid = threadIdx.x;
    const int bx = blockIdx.x, by = blockIdx.y;
    const int s  = blockIdx.z >> 2, bb = blockIdx.z & 3;
    const int l  = lmin + s;
    const int t  = d - l;

    const size_t S = (size_t)4 * HH * WW * 32;
    bf16* hlbase = (l == 0) ? h0 : (l == 1) ? h1 : (l == 2) ? h2 : h3;
    bf16*       hcur = hlbase + (size_t)((l == 0) ? (t & 3) : (t & 1)) * S;
    const bf16* hprv = hlbase + (size_t)((l == 0) ? ((t + 3) & 3) : ((t + 1) & 1)) * S;
    const bf16* hin  = (l == 1) ? h0 + (size_t)(t & 3) * S
                     : (l == 2) ? h1 + (size_t)(t & 1) * S
                     : (l == 3) ? h2 + (size_t)(t & 1) * S : nullptr;
    const bf16* resp = h0 + (size_t)(t & 3) * S;           // layer0 h at t (l==3)
    const float* bias = (l == 0) ? b0 : (l == 1) ? b1 : (l == 2) ? b2 : b3;
    float* cst = cbase + (size_t)l * S;

    const int lane = tid & 63;
    const int p    = tid >> 6;        // wave parity: nb = p + 2q
    const int col  = lane & 15;       // act pixel-x (B-col) / output pixel-x
    const int krow = lane >> 4;       // k-octet / C row block (cout sub-block)
    const int abase = col * ST + krow * 8;
    const int f0 = p * 16 + krow * 4; // 4 consecutive filters per thread

    // output pixel column for this thread; C row = cout (swapped layout)
    const size_t pb0 = (((size_t)bb * HH + by * 8) * WW + bx * 16 + col) * 32 + f0;
    const bf16* __restrict__ wb0 = Wt + (size_t)l * 73728 + (size_t)(p * 16 + col) * 64 + krow * 8;

    bf16x8 B0[2][4], B1[2][4];

#define LOAD_B(Bbuf, tap) do {                                               \
        const bf16* wt_ = wb0 + (size_t)(tap) * 8192;                        \
        _Pragma("unroll")                                                    \
        for (int q_ = 0; q_ < 4; ++q_) {                                     \
            Bbuf[0][q_] = *(const bf16x8*)(wt_ + q_ * 2048);                 \
            Bbuf[1][q_] = *(const bf16x8*)(wt_ + q_ * 2048 + 32);            \
        }                                                                    \
    } while (0)

    // ---- EARLY: tap-0 weights + c prefetch (8 f32x4, canonical layout) ----
    LOAD_B(B0, 0);
    f32x4 cpre4[8];
    #pragma unroll
    for (int i = 0; i < 8; ++i) cpre4[i] = (f32x4){0.f, 0.f, 0.f, 0.f};
    if (t > 0) {
        #pragma unroll
        for (int mt = 0; mt < 8; ++mt)
            cpre4[mt] = *(const f32x4*)(cst + pb0 + (size_t)mt * WW * 32);
    }

    // ---- staging: two half-batches of 6 (1440 items / 128 thr = 11.25) ----
    auto load_item = [&](int k, bf16x8& RH, bf16x8& RR) {
        RH = zero8(); RR = zero8();
        const int i = tid + k * 128;
        if (i < 180 * 8) {
            const int pix = i >> 3, g = i & 7;
            const int hy = pix / 18, hx = pix - hy * 18;
            const int sy = by * 8 - 1 + hy, sx = bx * 16 - 1 + hx;
            if (((unsigned)sy < HH) && ((unsigned)sx < WW)) {
                const size_t poff = (size_t)sy * WW + sx;
                if (g < 4) {
                    if (l == 0) {
                        if (g < 2) {               // raw-bit load of 8 fp32
                            const float* xp = x + ((size_t)(bb * 8 + t) * HH * WW + poff) * 16 + g * 8;
                            RH = *(const bf16x8*)xp;        // x[0..3] bits
                            RR = *(const bf16x8*)(xp + 4);  // x[4..7] bits
                        }
                    } else {
                        RH = *(const bf16x8*)(hin + ((size_t)bb * HH * WW + poff) * 32 + g * 8);
                        if (l == 3)
                            RR = *(const bf16x8*)(resp + ((size_t)bb * HH * WW + poff) * 32 + g * 8);
                    }
                } else if (t > 0) {
                    RH = *(const bf16x8*)(hprv + ((size_t)bb * HH * WW + poff) * 32 + (g - 4) * 8);
                }
            }
        }
    };
    auto store_item = [&](int k, const bf16x8& RH, const bf16x8& RR) {
        const int i = tid + k * 128;
        if (i < 180 * 8) {
            const int pix = i >> 3, g = i & 7;
            bf16x8 w;
            if (g < 4 && l == 0) {
                if (g < 2) {                      // bit-cast back, convert to bf16
                    const f32x4 a = __builtin_bit_cast(f32x4, RH);
                    const f32x4 b = __builtin_bit_cast(f32x4, RR);
                    w[0] = (bf16)a.x; w[1] = (bf16)a.y; w[2] = (bf16)a.z; w[3] = (bf16)a.w;
                    w[4] = (bf16)b.x; w[5] = (bf16)b.y; w[6] = (bf16)b.z; w[7] = (bf16)b.w;
                } else {
                    w = RH;                       // zero pad
                }
            } else if (g < 4 && l == 3) {         // residual add + relu
                #pragma unroll
                for (int j = 0; j < 8; ++j)
                    w[j] = (bf16)fmaxf((float)RH[j] + (float)RR[j], 0.f);
            } else if (g < 4 && l == 2) {         // relu only
                #pragma unroll
                for (int j = 0; j < 8; ++j)
                    w[j] = (bf16)fmaxf((float)RH[j], 0.f);
            } else {
                w = RH;                           // pure copy
            }
            *(bf16x8*)(&sact[pix * ST + g * 8]) = w;
        }
    };

    {
        bf16x8 rh[6], rr[6];
        #pragma unroll
        for (int k = 0; k < 6; ++k) load_item(k, rh[k], rr[k]);
        #pragma unroll
        for (int k = 0; k < 6; ++k) store_item(k, rh[k], rr[k]);
        #pragma unroll
        for (int k = 6; k < 12; ++k) load_item(k, rh[k - 6], rr[k - 6]);
        #pragma unroll
        for (int k = 6; k < 12; ++k) store_item(k, rh[k - 6], rr[k - 6]);
    }
    __syncthreads();

    // bias seeds: 4 f32x4 (component j = filter f0+j), uniform over mt
    f32x4 bseed4[4];
    #pragma unroll
    for (int q = 0; q < 4; ++q)
        bseed4[q] = *(const f32x4*)(bias + (p + 2 * q) * 16 + krow * 4);

    f32x4 acc2[8][4];                 // [mt = row-tile][q = gate]; reg j = filter
    #pragma unroll
    for (int q = 0; q < 4; ++q)
        #pragma unroll
        for (int mt = 0; mt < 8; ++mt) acc2[mt][q] = bseed4[q];

    // per tap: stream act per-mt; SWAPPED operands: mfma(W, act, acc) -> C^T
#define MFMA_TAP(Bbuf, tap) do {                                             \
        const int dy_ = (tap) / 3, dx_ = (tap) - dy_ * 3;                    \
        const int o_ = abase + (dy_ * 18 + dx_) * ST;                        \
        _Pragma("unroll")                                                    \
        for (int mt_ = 0; mt_ < 8; ++mt_) {                                  \
            const bf16x8 Aa = *(const bf16x8*)(&sact[o_ + mt_ * 18 * ST]);    \
            const bf16x8 Ab = *(const bf16x8*)(&sact[o_ + mt_ * 18 * ST + 32]);\
            __builtin_amdgcn_s_setprio(1);                                   \
            _Pragma("unroll")                                                \
            for (int q_ = 0; q_ < 4; ++q_)                                   \
                acc2[mt_][q_] = __builtin_amdgcn_mfma_f32_16x16x32_bf16(     \
                    Bbuf[0][q_], Aa, acc2[mt_][q_], 0, 0, 0);                \
            _Pragma("unroll")                                                \
            for (int q_ = 0; q_ < 4; ++q_)                                   \
                acc2[mt_][q_] = __builtin_amdgcn_mfma_f32_16x16x32_bf16(     \
                    Bbuf[1][q_], Ab, acc2[mt_][q_], 0, 0, 0);                \
            __builtin_amdgcn_s_setprio(0);                                   \
        }                                                                    \
    } while (0)

    #pragma unroll 1
    for (int k = 0; k < 4; ++k) {
        const int t1 = 2 * k + 1, t2 = 2 * k + 2;
        LOAD_B(B1, t1);
        MFMA_TAP(B0, 2 * k);
        LOAD_B(B0, t2);
        MFMA_TAP(B1, t1);
    }
    MFMA_TAP(B0, 8);   // tap 8

#undef LOAD_B
#undef MFMA_TAP

    // ---- epilogue: 4 consecutive filters per thread -> fully vectorized ----
    #pragma unroll
    for (int mt = 0; mt < 8; ++mt) {
        const size_t pb = pb0 + (size_t)mt * WW * 32;
        f32x4 cn4, hn4;
        #pragma unroll
        for (int j = 0; j < 4; ++j) {
            const float zi = acc2[mt][0][j];
            const float zf = acc2[mt][1][j];
            const float zg = acc2[mt][2][j];
            const float zo = acc2[mt][3][j];
            const float ig = hsig(zi), fg = hsig(zf);
            const float gg = ftanh(zg), og = hsig(zo);
            const float cn = fmaf(fg, cpre4[mt][j], ig * gg);
            cn4[j] = cn;
            hn4[j] = og * ftanh(cn);
        }
        if (t != 7) *(f32x4*)(cst + pb) = cn4;        // c(8) never read
        if (l == 3 && t == 7) {
            *(f32x4*)(outf + pb) = hn4;
        } else {
            bf16x4 hv;
            #pragma unroll
            for (int j = 0; j < 4; ++j) hv[j] = (bf16)hn4[j];
            *(bf16x4*)(hcur + pb) = hv;
        }
    }
}

extern "C" void kernel_launch(void* const* d_in, const int* in_sizes, int n_in,
                              void* d_out, int out_size, void* d_ws, size_t ws_size,
                              hipStream_t stream) {
    const float* x = (const float*)d_in[0];
    const float* Wx[4] = {(const float*)d_in[1], (const float*)d_in[4],
                          (const float*)d_in[7], (const float*)d_in[10]};
    const float* Wh[4] = {(const float*)d_in[2], (const float*)d_in[5],
                          (const float*)d_in[8], (const float*)d_in[11]};
    const float* bs[4] = {(const float*)d_in[3], (const float*)d_in[6],
                          (const float*)d_in[9], (const float*)d_in[12]};
    float* out = (float*)d_out;

    const size_t S  = (size_t)4 * HH * WW * 32;   // one [B,H,W,32] buffer (elements)
    const size_t WT = (size_t)4 * 73728;          // transposed weights (bf16 elems)

    bf16* wt = (bf16*)d_ws;
    bf16* h0 = wt + WT;              // layer0: 4-deep ring (residual read at d+3)
    bf16* h1 = h0 + 4 * S;           // layers 1..3: 2-deep rings
    bf16* h2 = h1 + 2 * S;
    bf16* h3 = h2 + 2 * S;
    float* cb = (float*)(h3 + 2 * S);   // 4 x S fp32 c-state (canonical layout)

    prep_weights<<<1152, 256, 0, stream>>>(Wx[0], Wh[0], Wx[1], Wh[1],
                                           Wx[2], Wh[2], Wx[3], Wh[3], wt);

    // Diagonal wavefront: d = t + l, stages (t, l) on one diagonal are independent.
    for (int d = 0; d <= 10; ++d) {
        const int lmin = (d > 7) ? (d - 7) : 0;
        const int lmax = (d < 3) ? d : 3;
        const int nst  = lmax - lmin + 1;
        dim3 grid(WW / 16, HH / 8, nst * 4);
        lstm_stage<<<grid, dim3(128), 0, stream>>>(
            x, wt, bs[0], bs[1], bs[2], bs[3],
            h0, h1, h2, h3, cb, out, d, lmin);
    }
}

// Round 24
// 453.676 us; speedup vs baseline: 1.5379x; 1.2917x over previous
//
#include <hip/hip_runtime.h>

#define HH 128
#define WW 128
#define HW (HH * WW)

typedef __bf16 bf16;
typedef bf16 bf16x4 __attribute__((ext_vector_type(4)));
typedef bf16 bf16x8 __attribute__((ext_vector_type(8)));
typedef float f32x4 __attribute__((ext_vector_type(4)));

__device__ __forceinline__ float hsig(float x) {
    return fminf(fmaxf(fmaf(0.2f, x, 0.5f), 0.f), 1.f);
}
__device__ __forceinline__ float ftanh(float x) {
    const float u = __expf(2.f * fminf(x, 40.f));
    return (u - 1.f) * __builtin_amdgcn_rcpf(u + 1.f);
}

// ---- one-time weight prep: fp32 [tap][ci][cout] -> bf16 Wt[l][tap][cout][ci64]
__global__ void prep_weights(const float* __restrict__ Wx0, const float* __restrict__ Wh0,
                             const float* __restrict__ Wx1, const float* __restrict__ Wh1,
                             const float* __restrict__ Wx2, const float* __restrict__ Wh2,
                             const float* __restrict__ Wx3, const float* __restrict__ Wh3,
                             bf16* __restrict__ Wt)
{
    int idx = blockIdx.x * 256 + threadIdx.x;      // 4*9*128*64 = 294912
    if (idx >= 4 * 9 * 128 * 64) return;
    const int l = idx / 73728;
    int r = idx - l * 73728;
    const int tap = r / (128 * 64);
    r -= tap * 128 * 64;
    const int co = r >> 6;
    const int ci = r & 63;
    const int CX = (l == 0) ? 16 : 32;
    const float* Wx = (l == 0) ? Wx0 : (l == 1) ? Wx1 : (l == 2) ? Wx2 : Wx3;
    const float* Wh = (l == 0) ? Wh0 : (l == 1) ? Wh1 : (l == 2) ? Wh2 : Wh3;
    float v = 0.f;
    if (ci < 32) { if (ci < CX) v = Wx[((size_t)tap * CX + ci) * 128 + co]; }
    else          v = Wh[((size_t)tap * 32 + (ci - 32)) * 128 + co];
    Wt[(size_t)l * 73728 + ((size_t)tap * 128 + co) * 64 + ci] = (bf16)v;
}

// ---- one-time: x fp32 -> bf16, and zero-page init ----
// Needs ALL 4*8*HW*16 = 8,388,608 elems -> 1,048,576 threads -> 4096 blocks.
__global__ void prep_x_zp(const float* __restrict__ x, bf16* __restrict__ xbf,
                          float* __restrict__ zp)
{
    const int idx = blockIdx.x * 256 + threadIdx.x;
    if (idx < 64) zp[idx] = 0.f;
    const int base = idx * 8;
    if (base < 4 * 8 * HW * 16) {
        const f32x4 a = *(const f32x4*)(x + base);
        const f32x4 b = *(const f32x4*)(x + base + 4);
        bf16x8 w;
        w[0] = (bf16)a.x; w[1] = (bf16)a.y; w[2] = (bf16)a.z; w[3] = (bf16)a.w;
        w[4] = (bf16)b.x; w[5] = (bf16)b.y; w[6] = (bf16)b.z; w[7] = (bf16)b.w;
        *(bf16x8*)(xbf + base) = w;
    }
}

// Diagonal-wavefront ConvLSTM stage. M=128/wave, swapped-operand C^T,
// vectorized epilogue. Staging = PURE COPY (bf16x8 load -> ds_write, 6+6
// split) into [c8][pix] LDS (A-reads stride-16B). Inputs pre-transformed:
// x pre-bf16; r2 = relu(h1) by l1's epilogue; r3 = relu(h2+h0) by l2's.
// OOB/pad/t=0 lanes read a zero-page (no staging math, uniform lanes).
__global__ __launch_bounds__(128, 2)
void lstm_stage(const bf16* __restrict__ xbf,
                const bf16* __restrict__ Wt,
                const float* __restrict__ b0, const float* __restrict__ b1,
                const float* __restrict__ b2, const float* __restrict__ b3,
                bf16* __restrict__ h0, bf16* __restrict__ h1,
                bf16* __restrict__ h2, bf16* __restrict__ h3,
                bf16* __restrict__ r2, bf16* __restrict__ r3,
                float* __restrict__ cbase,
                const float* __restrict__ zp,
                float* __restrict__ outf,
                const int d, const int lmin)
{
    __shared__ bf16 sact[12288];       // 1536 items x 8 bf16 (16B); [c8][pix]

    const int tid = threadIdx.x;
    const int bx = blockIdx.x, by = blockIdx.y;
    const int s  = blockIdx.z >> 2, bb = blockIdx.z & 3;
    const int l  = lmin + s;
    const int t  = d - l;

    const size_t S = (size_t)4 * HW * 32;
    bf16* hlbase = (l == 0) ? h0 : (l == 1) ? h1 : (l == 2) ? h2 : h3;
    bf16*       hcur = hlbase + (size_t)((l == 0) ? (t & 3) : (t & 1)) * S;
    const bf16* hprv = hlbase + (size_t)((l == 0) ? ((t + 3) & 3) : ((t + 1) & 1)) * S;
    const float* bias = (l == 0) ? b0 : (l == 1) ? b1 : (l == 2) ? b2 : b3;
    float* cst = cbase + (size_t)l * S;

    // block-uniform input descriptor (all inputs pre-transformed, pure copy)
    const bf16* inbase; int inchunks, instride;
    if (l == 0)      { inbase = xbf + (size_t)(bb * 8 + t) * HW * 16; inchunks = 2; instride = 16; }
    else if (l == 1) { inbase = h0 + (size_t)(t & 3) * S + (size_t)bb * HW * 32; inchunks = 4; instride = 32; }
    else if (l == 2) { inbase = r2 + (size_t)(t & 1) * S + (size_t)bb * HW * 32; inchunks = 4; instride = 32; }
    else             { inbase = r3 + (size_t)(t & 1) * S + (size_t)bb * HW * 32; inchunks = 4; instride = 32; }
    const bf16* hp = hprv + (size_t)bb * HW * 32;
    const bool hval = (t > 0);

    const int lane = tid & 63;
    const int p    = tid >> 6;        // wave parity: cout group
    const int col  = lane & 15;       // act pixel-x / output pixel-x
    const int krow = lane >> 4;       // k-octet / cout sub-block
    const int f0 = p * 16 + krow * 4; // 4 consecutive filters per thread

    const size_t pb0 = (((size_t)bb * HH + by * 8) * WW + bx * 16 + col) * 32 + f0;
    const bf16* __restrict__ wb0 = Wt + (size_t)l * 73728 + (size_t)(p * 16 + col) * 64 + krow * 8;

    bf16x8 B0[2][4], B1[2][4];

#define LOAD_B(Bbuf, tap) do {                                               \
        const bf16* wt_ = wb0 + (size_t)(tap) * 8192;                        \
        _Pragma("unroll")                                                    \
        for (int q_ = 0; q_ < 4; ++q_) {                                     \
            Bbuf[0][q_] = *(const bf16x8*)(wt_ + q_ * 2048);                 \
            Bbuf[1][q_] = *(const bf16x8*)(wt_ + q_ * 2048 + 32);            \
        }                                                                    \
    } while (0)

    // ---- EARLY: tap-0 weights + c prefetch ----
    LOAD_B(B0, 0);
    f32x4 cpre4[8];
    #pragma unroll
    for (int i = 0; i < 8; ++i) cpre4[i] = (f32x4){0.f, 0.f, 0.f, 0.f};
    if (t > 0) {
        #pragma unroll
        for (int mt = 0; mt < 8; ++mt)
            cpre4[mt] = *(const f32x4*)(cst + pb0 + (size_t)mt * WW * 32);
    }

    // ---- staging: pure 16B copies, item = c8*180 + pix; 6+6 split ----
    auto item_src = [&](int item) -> const bf16* {
        const unsigned c8  = (unsigned)item / 180u;
        const unsigned pix = (unsigned)item - c8 * 180u;
        const int hy = (int)(pix / 18u);
        const int hx = (int)pix - hy * 18;
        const int sy = by * 8 - 1 + hy, sx = bx * 16 - 1 + hx;
        const bool inb = ((unsigned)sy < HH) && ((unsigned)sx < WW) && (c8 < 8u);
        const int poff = sy * WW + sx;
        const bf16* src;
        if (c8 < 4u) src = ((int)c8 < inchunks)
                         ? inbase + (size_t)poff * instride + c8 * 8
                         : (const bf16*)zp;
        else         src = (hval && c8 < 8u)
                         ? hp + (size_t)poff * 32 + (c8 - 4u) * 8
                         : (const bf16*)zp;
        return inb ? src : (const bf16*)zp;
    };
    {
        bf16x8 v[6];
        #pragma unroll
        for (int k = 0; k < 6; ++k) v[k] = *(const bf16x8*)item_src(k * 128 + tid);
        #pragma unroll
        for (int k = 0; k < 6; ++k) *(bf16x8*)(&sact[(k * 128 + tid) * 8]) = v[k];
        #pragma unroll
        for (int k = 6; k < 12; ++k) v[k - 6] = *(const bf16x8*)item_src(k * 128 + tid);
        #pragma unroll
        for (int k = 6; k < 12; ++k) *(bf16x8*)(&sact[(k * 128 + tid) * 8]) = v[k - 6];
    }
    __syncthreads();

    // bias seeds + acc init
    f32x4 bseed4[4];
    #pragma unroll
    for (int q = 0; q < 4; ++q)
        bseed4[q] = *(const f32x4*)(bias + (p + 2 * q) * 16 + krow * 4);
    f32x4 acc2[8][4];
    #pragma unroll
    for (int q = 0; q < 4; ++q)
        #pragma unroll
        for (int mt = 0; mt < 8; ++mt) acc2[mt][q] = bseed4[q];

    // A cell (c8, pix) at elems c8*1440 + pix*8; Aa: c8=krow, Ab: c8=krow+4.
#define MFMA_TAP(Bbuf, tap) do {                                             \
        const int dy_ = (tap) / 3, dx_ = (tap) - dy_ * 3;                    \
        const int o0_ = krow * 1440 + (dy_ * 18 + dx_ + col) * 8;            \
        _Pragma("unroll")                                                    \
        for (int mt_ = 0; mt_ < 8; ++mt_) {                                  \
            const bf16x8 Aa = *(const bf16x8*)(&sact[o0_ + mt_ * 144]);       \
            const bf16x8 Ab = *(const bf16x8*)(&sact[o0_ + 5760 + mt_ * 144]);\
            __builtin_amdgcn_s_setprio(1);                                   \
            _Pragma("unroll")                                                \
            for (int q_ = 0; q_ < 4; ++q_)                                   \
                acc2[mt_][q_] = __builtin_amdgcn_mfma_f32_16x16x32_bf16(     \
                    Bbuf[0][q_], Aa, acc2[mt_][q_], 0, 0, 0);                \
            _Pragma("unroll")                                                \
            for (int q_ = 0; q_ < 4; ++q_)                                   \
                acc2[mt_][q_] = __builtin_amdgcn_mfma_f32_16x16x32_bf16(     \
                    Bbuf[1][q_], Ab, acc2[mt_][q_], 0, 0, 0);                \
            __builtin_amdgcn_s_setprio(0);                                   \
        }                                                                    \
    } while (0)

    #pragma unroll 1
    for (int k = 0; k < 4; ++k) {
        const int t1 = 2 * k + 1, t2 = 2 * k + 2;
        LOAD_B(B1, t1);
        MFMA_TAP(B0, 2 * k);
        LOAD_B(B0, t2);
        MFMA_TAP(B1, t1);
    }
    MFMA_TAP(B0, 8);   // tap 8

#undef LOAD_B
#undef MFMA_TAP

    // ---- epilogue: vectorized; producers pre-transform for consumers ----
    bf16x4 h0r[8];
    if (l == 2) {
        const bf16* h0t = h0 + (size_t)(t & 3) * S;
        #pragma unroll
        for (int mt = 0; mt < 8; ++mt)
            h0r[mt] = *(const bf16x4*)(h0t + pb0 + (size_t)mt * WW * 32);
    }
    bf16* r2w = r2 + (size_t)(t & 1) * S;
    bf16* r3w = r3 + (size_t)(t & 1) * S;

    #pragma unroll
    for (int mt = 0; mt < 8; ++mt) {
        const size_t pb = pb0 + (size_t)mt * WW * 32;
        f32x4 cn4, hn4;
        #pragma unroll
        for (int j = 0; j < 4; ++j) {
            const float zi = acc2[mt][0][j];
            const float zf = acc2[mt][1][j];
            const float zg = acc2[mt][2][j];
            const float zo = acc2[mt][3][j];
            const float ig = hsig(zi), fg = hsig(zf);
            const float gg = ftanh(zg), og = hsig(zo);
            const float cn = fmaf(fg, cpre4[mt][j], ig * gg);
            cn4[j] = cn;
            hn4[j] = og * ftanh(cn);
        }
        if (t != 7) *(f32x4*)(cst + pb) = cn4;        // c(8) never read
        if (l == 3 && t == 7) {
            *(f32x4*)(outf + pb) = hn4;
        } else {
            bf16x4 hv;
            #pragma unroll
            for (int j = 0; j < 4; ++j) hv[j] = (bf16)hn4[j];
            *(bf16x4*)(hcur + pb) = hv;
            if (l == 1) {                 // r2 = relu(h1), exact in bf16
                bf16x4 rv;
                #pragma unroll
                for (int j = 0; j < 4; ++j)
                    rv[j] = ((float)hv[j] > 0.f) ? hv[j] : (bf16)0.f;
                *(bf16x4*)(r2w + pb) = rv;
            } else if (l == 2) {          // r3 = relu(h2 + h0[t])
                bf16x4 rv;
                #pragma unroll
                for (int j = 0; j < 4; ++j)
                    rv[j] = (bf16)fmaxf((float)hv[j] + (float)h0r[mt][j], 0.f);
                *(bf16x4*)(r3w + pb) = rv;
            }
        }
    }
}

extern "C" void kernel_launch(void* const* d_in, const int* in_sizes, int n_in,
                              void* d_out, int out_size, void* d_ws, size_t ws_size,
                              hipStream_t stream) {
    const float* x = (const float*)d_in[0];
    const float* Wx[4] = {(const float*)d_in[1], (const float*)d_in[4],
                          (const float*)d_in[7], (const float*)d_in[10]};
    const float* Wh[4] = {(const float*)d_in[2], (const float*)d_in[5],
                          (const float*)d_in[8], (const float*)d_in[11]};
    const float* bs[4] = {(const float*)d_in[3], (const float*)d_in[6],
                          (const float*)d_in[9], (const float*)d_in[12]};
    float* out = (float*)d_out;

    const size_t S  = (size_t)4 * HW * 32;        // one [B,H,W,32] image (elems)
    const size_t WT = (size_t)4 * 73728;          // weights (bf16 elems)

    float* zp = (float*)d_ws;                     // 64-float zero page
    bf16* wt  = (bf16*)(zp + 64);
    bf16* xbf = wt + WT;                          // 4S elems (B,T,H,W,16)
    bf16* h0  = xbf + 4 * S;                      // 4-deep ring
    bf16* h1  = h0 + 4 * S;                       // 2-deep rings
    bf16* h2  = h1 + 2 * S;
    bf16* h3  = h2 + 2 * S;
    bf16* r2  = h3 + 2 * S;                       // relu(h1), 2-deep
    bf16* r3  = r2 + 2 * S;                       // relu(h2+h0), 2-deep
    float* cb = (float*)(r3 + 2 * S);             // 4 x S fp32 c-state

    prep_weights<<<1152, 256, 0, stream>>>(Wx[0], Wh[0], Wx[1], Wh[1],
                                           Wx[2], Wh[2], Wx[3], Wh[3], wt);
    prep_x_zp<<<4096, 256, 0, stream>>>(x, xbf, zp);   // FIXED: full coverage

    // Diagonal wavefront: d = t + l, stages on one diagonal are independent.
    for (int d = 0; d <= 10; ++d) {
        const int lmin = (d > 7) ? (d - 7) : 0;
        const int lmax = (d < 3) ? d : 3;
        const int nst  = lmax - lmin + 1;
        dim3 grid(WW / 16, HH / 8, nst * 4);
        lstm_stage<<<grid, dim3(128), 0, stream>>>(
            xbf, wt, bs[0], bs[1], bs[2], bs[3],
            h0, h1, h2, h3, r2, r3, cb, zp, out, d, lmin);
    }
}